// Round 16
// baseline (548.305 us; speedup 1.0000x reference)
//
#include <hip/hip_runtime.h>
#include <math.h>

// ---------------------------------------------------------------------------
// VQ-VAE forward. R16: enc_m + vq_m FUSED into k_encvq (z never touches
// global memory; vq A-fragments built directly from stage2 accumulators;
// LDS phase-aliased: vqa overlays a1 after its last read). Arithmetic
// bit-identical to R15. Buffers: q in regB (no alias with live h1).
//  conv1: x -> h1 f32                        [regA]
//  encvq: h1 -> q f32 [regB] + loss          (conv2+relu+conv3+VQ, one kernel)
//  tconv1 MFMA: q -> d1 bf16                 [regB upper]
//  tconv2 MFMA: d1 -> d2 bf16                [regA]
//  convf k3s1p1+sigm -> out
// ---------------------------------------------------------------------------

typedef __attribute__((ext_vector_type(8))) short s8v;   // 8 bf16 frag
typedef __attribute__((ext_vector_type(4))) float f4v;   // MFMA acc
typedef __attribute__((ext_vector_type(4))) int i4v;

__device__ inline unsigned short f2bf(float f) {  // RNE fp32->bf16
    unsigned u = __builtin_bit_cast(unsigned, f);
    return (unsigned short)((u + 0x7fffu + ((u >> 16) & 1u)) >> 16);
}
__device__ inline float bf2f(unsigned short h) {
    return __builtin_bit_cast(float, ((unsigned)h) << 16);
}

// ---- fused prep: cbm | B2n | B1 | B2 | B3 | cn | loss-zero ------------------
__global__ __launch_bounds__(256) void k_prep_all(
        const float* __restrict__ cb,  const float* __restrict__ ew2,
        const float* __restrict__ ew3, const float* __restrict__ dw1,
        const float* __restrict__ dw2,
        unsigned short* __restrict__ cbm, unsigned short* __restrict__ wB2n,
        unsigned short* __restrict__ wB1, unsigned short* __restrict__ wB2,
        unsigned short* __restrict__ wB3, float* __restrict__ cn,
        float* __restrict__ loss) {
    int i = blockIdx.x * 256 + threadIdx.x;
    if (i < 98304) {
        int j = i & 7, lane = (i >> 3) & 63;
        int kc = (i >> 9) % 6, nt = (i >> 9) / 6;
        int n = nt * 16 + (lane & 15);
        int k = kc * 32 + ((lane >> 4) << 3) + j;
        int seg = k >> 6, kk = k & 63;
        float c = cb[n * 64 + kk];
        unsigned short ch = f2bf(c);
        cbm[i] = (seg == 1) ? f2bf(c - bf2f(ch)) : ch;
    } else if (i < 153600) {
        int q = i - 98304;
        int j = q & 7, lane = (q >> 3) & 63;
        int kc = (q >> 9) % 27, nt = (q >> 9) / 27;
        int k = kc * 32 + ((lane >> 4) << 3) + j;
        int co = nt * 16 + (lane & 15);
        int part = (k < 288) ? 0 : (k < 576) ? 1 : 0;
        int kk = (k < 288) ? k : (k < 576) ? k - 288 : k - 576;
        int tap = kk >> 5, ci = kk & 31;
        float v = ew2[(co * 32 + ci) * 9 + tap];
        unsigned short hi = f2bf(v);
        wB2n[q] = part ? f2bf(v - bf2f(hi)) : hi;
    } else if (i < 219136) {
        int q = i - 153600;
        int j = q & 7, l = (q >> 3) & 63, kc = (q >> 9) & 7, nt = q >> 12;
        int n = nt * 16 + (l & 15), k = kc * 32 + (l >> 4) * 8 + j;
        int cls = n >> 6, co = n & 63, p = k >> 6, ci = k & 63;
        int jh = -1, jw = -1;
        if (cls == 0)      { if (p == 0) { jh = 1; jw = 1; } }
        else if (cls == 1) { if (p == 1) { jh = 1; jw = 0; } else if (p == 0) { jh = 1; jw = 2; } }
        else if (cls == 2) { if (p == 2) { jh = 0; jw = 1; } else if (p == 0) { jh = 2; jw = 1; } }
        else { if (p == 3) { jh = 0; jw = 0; } else if (p == 2) { jh = 0; jw = 2; }
               else if (p == 1) { jh = 2; jw = 0; } else { jh = 2; jw = 2; } }
        float v = (jh >= 0) ? dw1[((co * 64 + ci) * 3 + jh) * 3 + jw] : 0.f;
        wB1[q] = f2bf(v);
    } else if (i < 251904) {
        int q = i - 219136;
        int j = q & 7, l = (q >> 3) & 63, kc = (q >> 9) & 7, nt = q >> 12;
        int n = nt * 16 + (l & 15), k = kc * 32 + (l >> 4) * 8 + j;
        int cls = n >> 5, co = n & 31, p = k >> 6, ci = k & 63;
        int jh = -1, jw = -1;
        if (cls == 0)      { if (p == 0) { jh = 1; jw = 1; } }
        else if (cls == 1) { if (p == 1) { jh = 1; jw = 0; } else if (p == 0) { jh = 1; jw = 2; } }
        else if (cls == 2) { if (p == 2) { jh = 0; jw = 1; } else if (p == 0) { jh = 2; jw = 1; } }
        else { if (p == 3) { jh = 0; jw = 0; } else if (p == 2) { jh = 0; jw = 2; }
               else if (p == 1) { jh = 2; jw = 0; } else { jh = 2; jw = 2; } }
        float v = (jh >= 0) ? dw2[((co * 64 + ci) * 3 + jh) * 3 + jw] : 0.f;
        wB2[q] = f2bf(v);
    } else if (i < 264192) {
        int q = i - 251904;
        int j = q & 7, lane = (q >> 3) & 63;
        int kc = (q >> 9) % 6, nt = (q >> 9) / 6;
        int k = kc * 32 + ((lane >> 4) << 3) + j;
        int n = nt * 16 + (lane & 15);
        int part = (k < 64) ? 0 : (k < 128) ? 1 : 0;
        int kk = (k < 64) ? k : (k < 128) ? k - 64 : k - 128;
        float v = ew3[n * 64 + kk];
        unsigned short hi = f2bf(v);
        wB3[q] = part ? f2bf(v - bf2f(hi)) : hi;
    } else if (i < 264704) {
        int k = i - 264192;
        const float* r = cb + k * 64;
        float s = 0.f;
#pragma unroll
        for (int c = 0; c < 64; ++c) s += r[c] * r[c];
        cn[k] = s;
    } else if (i == 264704) {
        *loss = 0.f;
    }
}

// ---- conv1: x (bc,50,50) -> h1 (bc,25,25,32) f32, relu ---------------------
__global__ __launch_bounds__(256) void k_conv1(const float* __restrict__ x,
                                               const float* __restrict__ w,
                                               const float* __restrict__ b,
                                               float* __restrict__ h1, int total) {
    __shared__ float4 wl4[72];
    float* wl = (float*)wl4;
    int tid = threadIdx.x;
    for (int t = tid; t < 288; t += 256) {
        int tap = t >> 5, co = t & 31;
        wl[t] = w[co * 9 + tap];
    }
    __syncthreads();
    int pix = blockIdx.x * 256 + tid;
    if (pix >= total) return;
    int n = pix / 625, p = pix % 625, oh = p / 25, ow = p % 25;
    const float* xp = x + (size_t)n * 2500;
    float4 a[8];
#pragma unroll
    for (int j = 0; j < 8; ++j) a[j] = ((const float4*)b)[j];
#pragma unroll
    for (int kh = 0; kh < 3; ++kh) {
        int ih = 2 * oh - 1 + kh;
        if ((unsigned)ih >= 50u) continue;
#pragma unroll
        for (int kw = 0; kw < 3; ++kw) {
            int iw = 2 * ow - 1 + kw;
            if ((unsigned)iw >= 50u) continue;
            float v = xp[ih * 50 + iw];
            int tap = kh * 3 + kw;
#pragma unroll
            for (int j = 0; j < 8; ++j) {
                float4 ww = wl4[tap * 8 + j];
                a[j].x += v * ww.x; a[j].y += v * ww.y;
                a[j].z += v * ww.z; a[j].w += v * ww.w;
            }
        }
    }
    float4* op = (float4*)(h1 + (size_t)pix * 32);
#pragma unroll
    for (int j = 0; j < 8; ++j) {
        float4 r;
        r.x = fmaxf(a[j].x, 0.f); r.y = fmaxf(a[j].y, 0.f);
        r.z = fmaxf(a[j].z, 0.f); r.w = fmaxf(a[j].w, 0.f);
        op[j] = r;
    }
}

// ---- encvq: conv2+relu+conv3 (split-bf16 MFMA) + VQ, fused. M=32/block -----
// Phase A: stage h1 patch -> a1 [hi288|lo288]. Phase B: stage1 27-kc MFMAs
// -> a2 [hi64|lo64]. Phase C: stage2 6-kc MFMAs -> z in cz (fp32) AND vq
// A-layout [zh|zh|zl] into vqa (aliases a1 -- last a1 read was phase B,
// separated by a barrier). Phase D: VQ distance GEMM + argmin + q + loss.
__global__ __launch_bounds__(256) void k_encvq(const float* __restrict__ h1,
                                               const unsigned short* __restrict__ B2n,
                                               const unsigned short* __restrict__ B3,
                                               const float* __restrict__ b2,
                                               const float* __restrict__ b3,
                                               const float* __restrict__ cb,
                                               const unsigned short* __restrict__ cbm,
                                               const float* __restrict__ cn,
                                               float* __restrict__ q,
                                               float* __restrict__ loss, int npix) {
    __shared__ short a1[32 * 584];   // 36.5 KB; phase D: vqa (32*200) aliases front
    __shared__ short a2[32 * 136];   // 8.5 KB
    __shared__ float cz[32 * 68];    // 8.5 KB
    __shared__ float reds[4 * 32];
    __shared__ int   redk[4 * 32];
    __shared__ int   bkf[32];
    __shared__ float lred[4];
    short* vqa = a1;                 // alias, valid from phase C epilogue on
    int tid = threadIdx.x, blk = blockIdx.x;
    // ---- phase A: stage h1 patches ----
#pragma unroll
    for (int it = 0; it < 2; ++it) {
        int idx = tid + it * 256;
        if (idx < 288) {
            int m = idx / 9, chunk = idx % 9;
            int pix = blk * 32 + m;
            float4 v[8];
            const float4 zero = {0.f, 0.f, 0.f, 0.f};
            bool ok = false;
            if (pix < npix) {
                int n = pix / 169, p = pix % 169, oh = p / 13, ow = p % 13;
                int kh = chunk / 3, kw = chunk % 3;
                int ih = 2 * oh - 1 + kh, iw = 2 * ow - 1 + kw;
                ok = ((unsigned)ih < 25u) && ((unsigned)iw < 25u);
                if (ok) {
                    const float4* ip = (const float4*)(h1 + (((size_t)n * 25 + ih) * 25 + iw) * 32);
#pragma unroll
                    for (int c4 = 0; c4 < 8; ++c4) v[c4] = ip[c4];
                }
            }
            if (!ok) {
#pragma unroll
                for (int c4 = 0; c4 < 8; ++c4) v[c4] = zero;
            }
            unsigned short hi[32], lo[32];
#pragma unroll
            for (int c4 = 0; c4 < 8; ++c4) {
                float vv[4] = {v[c4].x, v[c4].y, v[c4].z, v[c4].w};
#pragma unroll
                for (int e = 0; e < 4; ++e) {
                    int ci = c4 * 4 + e;
                    unsigned short h = f2bf(vv[e]);
                    hi[ci] = h;
                    lo[ci] = f2bf(vv[e] - bf2f(h));
                }
            }
            short* row = a1 + m * 584;
            i4v* dh = (i4v*)(row + chunk * 32);
            i4v* dl = (i4v*)(row + 288 + chunk * 32);
#pragma unroll
            for (int g = 0; g < 4; ++g) {
                i4v ph, pl;
#pragma unroll
                for (int e = 0; e < 4; ++e) {
                    int b0 = g * 8 + e * 2;
                    ph[e] = (int)((unsigned)hi[b0] | ((unsigned)hi[b0 + 1] << 16));
                    pl[e] = (int)((unsigned)lo[b0] | ((unsigned)lo[b0 + 1] << 16));
                }
                dh[g] = ph; dl[g] = pl;
            }
        }
    }
    __syncthreads();
    int wave = tid >> 6, lane = tid & 63;
    int acol = (lane >> 4) * 8;
    // ---- phase B: stage1 MFMAs ----
    {
        f4v acc[2];
        acc[0] = (f4v){0.f, 0.f, 0.f, 0.f};
        acc[1] = acc[0];
#pragma unroll
        for (int kc = 0; kc < 27; ++kc) {
            int aoff = (kc < 9) ? kc * 32 : (kc < 18) ? (kc - 9) * 32 : 288 + (kc - 18) * 32;
            s8v b = *(const s8v*)((const short*)B2n + ((size_t)((wave * 27 + kc) * 64 + lane)) * 8);
#pragma unroll
            for (int mt = 0; mt < 2; ++mt) {
                s8v a = *(const s8v*)(a1 + (mt * 16 + (lane & 15)) * 584 + acol + aoff);
                acc[mt] = __builtin_amdgcn_mfma_f32_16x16x32_bf16(a, b, acc[mt], 0, 0, 0);
            }
        }
        float bv = b2[wave * 16 + (lane & 15)];
        int n = wave * 16 + (lane & 15);
#pragma unroll
        for (int mt = 0; mt < 2; ++mt)
#pragma unroll
            for (int r = 0; r < 4; ++r) {
                int m = mt * 16 + (lane >> 4) * 4 + r;
                float h = fmaxf(acc[mt][r] + bv, 0.f);
                unsigned short hh = f2bf(h);
                unsigned short ll = f2bf(h - bf2f(hh));
                a2[m * 136 + n] = (short)hh;
                a2[m * 136 + 64 + n] = (short)ll;
            }
    }
    __syncthreads();   // a1 reads done; a2 ready
    // ---- phase C: stage2 MFMAs -> z (cz) + vq A-layout (vqa, aliases a1) ----
    {
        f4v acc2[2];
        acc2[0] = (f4v){0.f, 0.f, 0.f, 0.f};
        acc2[1] = acc2[0];
#pragma unroll
        for (int kc = 0; kc < 6; ++kc) {
            int aoff = (kc < 2) ? kc * 32 : (kc < 4) ? (kc - 2) * 32 : 64 + (kc - 4) * 32;
            s8v b = *(const s8v*)((const short*)B3 + ((size_t)((wave * 6 + kc) * 64 + lane)) * 8);
#pragma unroll
            for (int mt = 0; mt < 2; ++mt) {
                s8v a = *(const s8v*)(a2 + (mt * 16 + (lane & 15)) * 136 + acol + aoff);
                acc2[mt] = __builtin_amdgcn_mfma_f32_16x16x32_bf16(a, b, acc2[mt], 0, 0, 0);
            }
        }
        float bv = b3[wave * 16 + (lane & 15)];
        int n = wave * 16 + (lane & 15);
#pragma unroll
        for (int mt = 0; mt < 2; ++mt)
#pragma unroll
            for (int r = 0; r < 4; ++r) {
                int m = mt * 16 + (lane >> 4) * 4 + r;
                float zv = acc2[mt][r] + bv;
                cz[m * 68 + n] = zv;
                unsigned short zh = f2bf(zv);
                unsigned short zl = f2bf(zv - bf2f(zh));
                vqa[m * 200 + n] = (short)zh;
                vqa[m * 200 + 64 + n] = (short)zh;
                vqa[m * 200 + 128 + n] = (short)zl;
            }
    }
    __syncthreads();
    // ---- phase D: VQ distance GEMM + argmin + q + loss ----
    s8v af[2][6];
#pragma unroll
    for (int mt = 0; mt < 2; ++mt) {
        int arow = (mt * 16 + (lane & 15)) * 200 + (lane >> 4) * 8;
#pragma unroll
        for (int kc = 0; kc < 6; ++kc)
            af[mt][kc] = *(const s8v*)(vqa + arow + kc * 32);
    }
    float bd[2][4];
    int bk[2][4];
#pragma unroll
    for (int mt = 0; mt < 2; ++mt)
#pragma unroll
        for (int r = 0; r < 4; ++r) { bd[mt][r] = 3.4e38f; bk[mt][r] = 0; }
#pragma unroll 2
    for (int nt = 0; nt < 8; ++nt) {
        int ntg = wave * 8 + nt;
        s8v bf[6];
#pragma unroll
        for (int kc = 0; kc < 6; ++kc)
            bf[kc] = *(const s8v*)((const short*)cbm + ((size_t)((ntg * 6 + kc) * 64 + lane)) * 8);
        f4v acc0 = (f4v){0.f, 0.f, 0.f, 0.f};
        f4v acc1 = (f4v){0.f, 0.f, 0.f, 0.f};
#pragma unroll
        for (int kc = 0; kc < 6; ++kc) {
            acc0 = __builtin_amdgcn_mfma_f32_16x16x32_bf16(af[0][kc], bf[kc], acc0, 0, 0, 0);
            acc1 = __builtin_amdgcn_mfma_f32_16x16x32_bf16(af[1][kc], bf[kc], acc1, 0, 0, 0);
        }
        int kcol = ntg * 16 + (lane & 15);
        float cnk = cn[kcol];
#pragma unroll
        for (int r = 0; r < 4; ++r) {
            float d0 = cnk - 2.f * acc0[r];
            if (d0 < bd[0][r]) { bd[0][r] = d0; bk[0][r] = kcol; }
            float d1 = cnk - 2.f * acc1[r];
            if (d1 < bd[1][r]) { bd[1][r] = d1; bk[1][r] = kcol; }
        }
    }
#pragma unroll
    for (int off = 1; off < 16; off <<= 1) {
#pragma unroll
        for (int mt = 0; mt < 2; ++mt)
#pragma unroll
            for (int r = 0; r < 4; ++r) {
                float od = __shfl_xor(bd[mt][r], off);
                int ok = __shfl_xor(bk[mt][r], off);
                if (od < bd[mt][r] || (od == bd[mt][r] && ok < bk[mt][r])) {
                    bd[mt][r] = od; bk[mt][r] = ok;
                }
            }
    }
    if ((lane & 15) == 0) {
#pragma unroll
        for (int mt = 0; mt < 2; ++mt)
#pragma unroll
            for (int r = 0; r < 4; ++r) {
                int m = mt * 16 + (lane >> 4) * 4 + r;
                reds[wave * 32 + m] = bd[mt][r];
                redk[wave * 32 + m] = bk[mt][r];
            }
    }
    __syncthreads();
    if (tid < 32) {
        float d0 = reds[tid]; int k0 = redk[tid];
#pragma unroll
        for (int w = 1; w < 4; ++w) {
            float dw = reds[w * 32 + tid]; int kw = redk[w * 32 + tid];
            if (dw < d0 || (dw == d0 && kw < k0)) { d0 = dw; k0 = kw; }
        }
        bkf[tid] = k0;
    }
    __syncthreads();
    float lsum = 0.f;
#pragma unroll
    for (int it = 0; it < 2; ++it) {
        int m = tid >> 3, c4 = (tid & 7) + it * 8;
        int pix = blk * 32 + m;
        if (pix < npix) {
            int k0 = bkf[m];
            float4 cq = ((const float4*)cb)[(size_t)k0 * 16 + c4];
            float4 zz = *(float4*)(cz + m * 68 + c4 * 4);
            float dx = cq.x - zz.x, dy = cq.y - zz.y, dz = cq.z - zz.z, dw = cq.w - zz.w;
            lsum += dx * dx + dy * dy + dz * dz + dw * dw;
            ((float4*)(q + (size_t)pix * 64))[c4] = cq;
        }
    }
#pragma unroll
    for (int off = 32; off > 0; off >>= 1) lsum += __shfl_down(lsum, off);
    if ((tid & 63) == 0) lred[tid >> 6] = lsum;
    __syncthreads();
    if (tid == 0) {
        float t = lred[0] + lred[1] + lred[2] + lred[3];
        atomicAdd(loss, t * (1.25f / 11075584.f));
    }
}

// ---- tconv1 MFMA: q f32 -> d1 bf16 (25,25,64), relu. M=32/block ------------
__global__ __launch_bounds__(256) void k_tconv1_m(const float* __restrict__ q,
                                                  const unsigned short* __restrict__ wB,
                                                  const float* __restrict__ bias,
                                                  unsigned short* __restrict__ d1,
                                                  int nquad) {
    __shared__ short a_lds[32 * 264];
    __shared__ short c_lds[32 * 264];
    int tid = threadIdx.x, blk = blockIdx.x;
#pragma unroll
    for (int pass = 0; pass < 4; ++pass) {
        int idx = tid + pass * 256;
        int m = idx >> 5, sub = idx & 31;
        int qg = blk * 32 + m;
        int p = sub >> 3, ci0 = (sub & 7) * 8;
        unsigned short t8[8];
        bool have = false;
        if (qg < nquad) {
            int img = qg / 169, r = qg % 169, qm = r / 13, qw = r % 13;
            int sm = qm + (p >> 1), sw = qw + (p & 1);
            if (sm < 13 && sw < 13) {
                const float* src = q + (((size_t)img * 13 + sm) * 13 + sw) * 64 + ci0;
#pragma unroll
                for (int v = 0; v < 8; ++v) t8[v] = f2bf(src[v]);
                have = true;
            }
        }
        if (!have) {
#pragma unroll
            for (int v = 0; v < 8; ++v) t8[v] = 0;
        }
        i4v pk;
#pragma unroll
        for (int e = 0; e < 4; ++e)
            pk[e] = (int)((unsigned)t8[2 * e] | ((unsigned)t8[2 * e + 1] << 16));
        *(i4v*)(a_lds + m * 264 + sub * 8) = pk;
    }
    __syncthreads();
    int wave = tid >> 6, lane = tid & 63;
    f4v acc[2][4];
#pragma unroll
    for (int mt = 0; mt < 2; ++mt)
#pragma unroll
        for (int i = 0; i < 4; ++i) acc[mt][i] = (f4v){0.f, 0.f, 0.f, 0.f};
    float bv[4];
#pragma unroll
    for (int i = 0; i < 4; ++i) bv[i] = bias[((wave * 4 + i) * 16 + (lane & 15)) & 63];
#pragma unroll
    for (int kc = 0; kc < 8; ++kc) {
        s8v a0 = *(const s8v*)(a_lds + ((lane & 15)) * 264 + (lane >> 4) * 8 + kc * 32);
        s8v a1 = *(const s8v*)(a_lds + (16 + (lane & 15)) * 264 + (lane >> 4) * 8 + kc * 32);
#pragma unroll
        for (int i = 0; i < 4; ++i) {
            int nt = wave * 4 + i;
            s8v b = *(const s8v*)((const short*)wB + ((size_t)((nt * 8 + kc) * 64 + lane)) * 8);
            acc[0][i] = __builtin_amdgcn_mfma_f32_16x16x32_bf16(a0, b, acc[0][i], 0, 0, 0);
            acc[1][i] = __builtin_amdgcn_mfma_f32_16x16x32_bf16(a1, b, acc[1][i], 0, 0, 0);
        }
    }
#pragma unroll
    for (int mt = 0; mt < 2; ++mt)
#pragma unroll
        for (int i = 0; i < 4; ++i) {
            int n = (wave * 4 + i) * 16 + (lane & 15);
#pragma unroll
            for (int r2 = 0; r2 < 4; ++r2) {
                int m = mt * 16 + (lane >> 4) * 4 + r2;
                float v = fmaxf(acc[mt][i][r2] + bv[i], 0.f);
                c_lds[m * 264 + n] = (short)f2bf(v);
            }
        }
    __syncthreads();
#pragma unroll
    for (int pass = 0; pass < 4; ++pass) {
        int ch = tid + pass * 256;
        int m = ch >> 5, cpart = ch & 31;
        int qg = blk * 32 + m;
        if (qg >= nquad) continue;
        int img = qg / 169, r = qg % 169, qm = r / 13, qw = r % 13;
        int cls = cpart >> 3, co8 = (cpart & 7) * 8;
        int oh = 2 * qm + (cls >> 1), ow = 2 * qw + (cls & 1);
        if (oh >= 25 || ow >= 25) continue;
        i4v val = *(i4v*)(c_lds + m * 264 + cls * 64 + co8);
        *(i4v*)(d1 + (((size_t)img * 25 + oh) * 25 + ow) * 64 + co8) = val;
    }
}

// ---- tconv2 MFMA: d1 bf16 -> d2 bf16 (50,50,32), relu. M=32/block ----------
__global__ __launch_bounds__(256) void k_tconv2_m(const unsigned short* __restrict__ d1,
                                                  const unsigned short* __restrict__ wB,
                                                  const float* __restrict__ bias,
                                                  unsigned short* __restrict__ d2,
                                                  int nquad) {
    __shared__ short a_lds[32 * 264];
    __shared__ short c_lds[32 * 136];
    int tid = threadIdx.x, blk = blockIdx.x;
#pragma unroll
    for (int pass = 0; pass < 4; ++pass) {
        int idx = tid + pass * 256;
        int m = idx >> 5, sub = idx & 31;
        int qg = blk * 32 + m;
        int p = sub >> 3, ci0 = (sub & 7) * 8;
        i4v v = (i4v){0, 0, 0, 0};
        if (qg < nquad) {
            int img = qg / 625, r = qg % 625, qm = r / 25, qw = r % 25;
            int sm = qm + (p >> 1), sw = qw + (p & 1);
            if (sm < 25 && sw < 25)
                v = *(const i4v*)(d1 + (((size_t)img * 25 + sm) * 25 + sw) * 64 + ci0);
        }
        *(i4v*)(a_lds + m * 264 + sub * 8) = v;
    }
    __syncthreads();
    int wave = tid >> 6, lane = tid & 63;
    f4v acc[2][2];
#pragma unroll
    for (int mt = 0; mt < 2; ++mt)
#pragma unroll
        for (int i = 0; i < 2; ++i) acc[mt][i] = (f4v){0.f, 0.f, 0.f, 0.f};
    float bv[2];
#pragma unroll
    for (int i = 0; i < 2; ++i) bv[i] = bias[((wave * 2 + i) * 16 + (lane & 15)) & 31];
#pragma unroll
    for (int kc = 0; kc < 8; ++kc) {
        s8v a0 = *(const s8v*)(a_lds + ((lane & 15)) * 264 + (lane >> 4) * 8 + kc * 32);
        s8v a1 = *(const s8v*)(a_lds + (16 + (lane & 15)) * 264 + (lane >> 4) * 8 + kc * 32);
#pragma unroll
        for (int i = 0; i < 2; ++i) {
            int nt = wave * 2 + i;
            s8v b = *(const s8v*)((const short*)wB + ((size_t)((nt * 8 + kc) * 64 + lane)) * 8);
            acc[0][i] = __builtin_amdgcn_mfma_f32_16x16x32_bf16(a0, b, acc[0][i], 0, 0, 0);
            acc[1][i] = __builtin_amdgcn_mfma_f32_16x16x32_bf16(a1, b, acc[1][i], 0, 0, 0);
        }
    }
#pragma unroll
    for (int mt = 0; mt < 2; ++mt)
#pragma unroll
        for (int i = 0; i < 2; ++i) {
            int n = (wave * 2 + i) * 16 + (lane & 15);
#pragma unroll
            for (int r2 = 0; r2 < 4; ++r2) {
                int m = mt * 16 + (lane >> 4) * 4 + r2;
                float v = fmaxf(acc[mt][i][r2] + bv[i], 0.f);
                c_lds[m * 136 + n] = (short)f2bf(v);
            }
        }
    __syncthreads();
#pragma unroll
    for (int pass = 0; pass < 2; ++pass) {
        int ch = tid + pass * 256;
        int m = ch >> 4, cpart = ch & 15;
        int qg = blk * 32 + m;
        if (qg >= nquad) continue;
        int img = qg / 625, r = qg % 625, qm = r / 25, qw = r % 25;
        int cls = cpart >> 2, co8 = (cpart & 3) * 8;
        int oh = 2 * qm + (cls >> 1), ow = 2 * qw + (cls & 1);
        i4v val = *(i4v*)(c_lds + m * 136 + cls * 32 + co8);
        *(i4v*)(d2 + (((size_t)img * 50 + oh) * 50 + ow) * 32 + co8) = val;
    }
}

// ---- convf: d2 bf16 (bc,50,50,32) -> out f32 (bc,50,50), sigmoid -----------
__global__ __launch_bounds__(256) void k_convf(const unsigned short* __restrict__ in,
                                               const float* __restrict__ w,  // dw3 (1,32,3,3)
                                               const float* __restrict__ b,
                                               float* __restrict__ out, int total) {
    __shared__ float wl[288];  // [tap9][ci32]
    int tid = threadIdx.x;
    for (int t = tid; t < 288; t += 256) {
        int tap = t >> 5, ci = t & 31;
        wl[t] = w[ci * 9 + tap];
    }
    __syncthreads();
    int pix = blockIdx.x * 256 + tid;
    if (pix >= total) return;
    int n = pix / 2500, p = pix % 2500, oh = p / 50, ow = p % 50;
    float acc = b[0];
#pragma unroll
    for (int kh = 0; kh < 3; ++kh) {
        int ih = oh - 1 + kh;
        if ((unsigned)ih >= 50u) continue;
#pragma unroll
        for (int kw = 0; kw < 3; ++kw) {
            int iw = ow - 1 + kw;
            if ((unsigned)iw >= 50u) continue;
            const float* wt = wl + (kh * 3 + kw) * 32;
            const i4v* ip4 = (const i4v*)(in + (((size_t)n * 50 + ih) * 50 + iw) * 32);
#pragma unroll
            for (int c8 = 0; c8 < 4; ++c8) {
                i4v u = ip4[c8];
#pragma unroll
                for (int e = 0; e < 4; ++e) {
                    unsigned uu = (unsigned)u[e];
                    float x0 = __builtin_bit_cast(float, uu << 16);
                    float x1 = __builtin_bit_cast(float, uu & 0xffff0000u);
                    acc = fmaf(x0, wt[c8 * 8 + e * 2], acc);
                    acc = fmaf(x1, wt[c8 * 8 + e * 2 + 1], acc);
                }
            }
        }
    }
    out[pix] = 1.f / (1.f + expf(-acc));
}

extern "C" void kernel_launch(void* const* d_in, const int* in_sizes, int n_in,
                              void* d_out, int out_size, void* d_ws, size_t ws_size,
                              hipStream_t stream) {
    const float* x   = (const float*)d_in[0];
    const float* ew1 = (const float*)d_in[1];
    const float* eb1 = (const float*)d_in[2];
    const float* ew2 = (const float*)d_in[3];
    const float* eb2 = (const float*)d_in[4];
    const float* ew3 = (const float*)d_in[5];
    const float* eb3 = (const float*)d_in[6];
    const float* cb  = (const float*)d_in[7];
    const float* dw1 = (const float*)d_in[8];
    const float* db1 = (const float*)d_in[9];
    const float* dw2 = (const float*)d_in[10];
    const float* db2 = (const float*)d_in[11];
    const float* dw3 = (const float*)d_in[12];
    const float* db3 = (const float*)d_in[13];
    float* out = (float*)d_out;
    float* loss = out + 2560000;

    float* ws = (float*)d_ws;
    float* cn = ws;                                        // 512 f
    unsigned short* wB1  = (unsigned short*)(ws + 512);    // 65536 sh
    unsigned short* wB2  = (unsigned short*)(ws + 33280);  // 32768 sh
    unsigned short* wB2n = (unsigned short*)(ws + 49664);  // 55296 sh
    unsigned short* wB3  = (unsigned short*)(ws + 77312);  // 12288 sh
    unsigned short* cbm  = (unsigned short*)(ws + 83456);  // 98304 sh
    const size_t tw_floats = 132608;

    const int B = 1024;
    // regA 40000 f/img: h1 (20000 f, dead after encvq), then d2 (80000 sh)
    // regB 30816 f/img: q (10816 f) + d1 (20000 f as 40000 sh)
    const size_t A_per = 40000, B_per = 30816;
    size_t avail = (ws_size / 4 > tw_floats) ? ws_size / 4 - tw_floats : 0;
    int BC = (int)(avail / (A_per + B_per));
    if (BC > B) BC = B;
    if (BC < 1) BC = 1;
    float* regA = ws + tw_floats;
    float* regB = regA + (size_t)BC * A_per;

    k_prep_all<<<1035, 256, 0, stream>>>(cb, ew2, ew3, dw1, dw2,
                                         cbm, wB2n, wB1, wB2, wB3, cn, loss);

    for (int n0 = 0; n0 < B; n0 += BC) {
        int bc = (B - n0 < BC) ? (B - n0) : BC;
        const float* xch = x + (size_t)n0 * 2500;

        int t1 = bc * 625;   // conv1: x -> h1 (regA)
        k_conv1<<<(t1 + 255) / 256, 256, 0, stream>>>(xch, ew1, eb1, regA, t1);

        int npix = bc * 169;
        // fused conv2+conv3+VQ: h1 (regA) -> q (regB) + loss
        float* qbuf = regB;
        k_encvq<<<(npix + 31) / 32, 256, 0, stream>>>(regA, wB2n, wB3, eb2, eb3,
                                                      cb, cbm, cn, qbuf, loss, npix);

        // tconv1 MFMA: q (regB) -> d1 (regB upper, bf16)
        unsigned short* d1 = (unsigned short*)(regB + (size_t)BC * 10816);
        k_tconv1_m<<<(npix + 31) / 32, 256, 0, stream>>>(qbuf, wB1, db1, d1, npix);

        // tconv2 MFMA: d1 -> d2 (regA, bf16; h1 dead)
        int nq2 = bc * 625;
        unsigned short* d2 = (unsigned short*)regA;
        k_tconv2_m<<<(nq2 + 31) / 32, 256, 0, stream>>>(d1, wB2, db2, d2, nq2);

        int t6 = bc * 2500;  // convf: d2 (regA) -> out
        k_convf<<<(t6 + 255) / 256, 256, 0, stream>>>(d2, dw3, db3, out + (size_t)n0 * 2500, t6);
    }
}

// Round 17
// 503.549 us; speedup vs baseline: 1.0889x; 1.0889x over previous
//
#include <hip/hip_runtime.h>
#include <math.h>

// ---------------------------------------------------------------------------
// VQ-VAE forward. R17 = best measured combination:
//  - fused prep (R14), - enc_m M=16 (R13), - vq_m M=32 (R13),
//  - tconv1/tconv2 M=32 (R13), - convf.
//  conv1: x -> h1 (n,25,25,32) f32            [regA]
//  enc_m: h1 -> z (n,13,13,64) f32            [regB]
//  vq_m:  z -> q f32 [regA] + loss
//  tconv1 MFMA: q -> d1 (n,25,25,64) bf16     [regB]
//  tconv2 MFMA: d1 -> d2 (n,50,50,32) bf16    [regA]
//  convf k3s1p1+sigm (bf16 in, fp32 math) -> out (n,50,50)
// ---------------------------------------------------------------------------

typedef __attribute__((ext_vector_type(8))) short s8v;   // 8 bf16 frag
typedef __attribute__((ext_vector_type(4))) float f4v;   // MFMA acc
typedef __attribute__((ext_vector_type(4))) int i4v;

__device__ inline unsigned short f2bf(float f) {  // RNE fp32->bf16
    unsigned u = __builtin_bit_cast(unsigned, f);
    return (unsigned short)((u + 0x7fffu + ((u >> 16) & 1u)) >> 16);
}
__device__ inline float bf2f(unsigned short h) {
    return __builtin_bit_cast(float, ((unsigned)h) << 16);
}

// ---- fused prep: cbm | B2n | B1 | B2 | B3 | cn | loss-zero ------------------
__global__ __launch_bounds__(256) void k_prep_all(
        const float* __restrict__ cb,  const float* __restrict__ ew2,
        const float* __restrict__ ew3, const float* __restrict__ dw1,
        const float* __restrict__ dw2,
        unsigned short* __restrict__ cbm, unsigned short* __restrict__ wB2n,
        unsigned short* __restrict__ wB1, unsigned short* __restrict__ wB2,
        unsigned short* __restrict__ wB3, float* __restrict__ cn,
        float* __restrict__ loss) {
    int i = blockIdx.x * 256 + threadIdx.x;
    if (i < 98304) {
        // cbm: VQ codebook 3-product split (nt32, kc6, lane64, j8)
        int j = i & 7, lane = (i >> 3) & 63;
        int kc = (i >> 9) % 6, nt = (i >> 9) / 6;
        int n = nt * 16 + (lane & 15);
        int k = kc * 32 + ((lane >> 4) << 3) + j;
        int seg = k >> 6, kk = k & 63;
        float c = cb[n * 64 + kk];
        unsigned short ch = f2bf(c);
        cbm[i] = (seg == 1) ? f2bf(c - bf2f(ch)) : ch;
    } else if (i < 153600) {
        // B2n: conv2 split (nt4, kc27, lane64, j8); K1=864 = [hi288|lo288|hi288]
        int q = i - 98304;
        int j = q & 7, lane = (q >> 3) & 63;
        int kc = (q >> 9) % 27, nt = (q >> 9) / 27;
        int k = kc * 32 + ((lane >> 4) << 3) + j;
        int co = nt * 16 + (lane & 15);
        int part = (k < 288) ? 0 : (k < 576) ? 1 : 0;
        int kk = (k < 288) ? k : (k < 576) ? k - 288 : k - 576;
        int tap = kk >> 5, ci = kk & 31;
        float v = ew2[(co * 32 + ci) * 9 + tap];
        unsigned short hi = f2bf(v);
        wB2n[q] = part ? f2bf(v - bf2f(hi)) : hi;
    } else if (i < 219136) {
        // B1: tconv1 zero-padded (nt16, kc8, lane64, j8)
        int q = i - 153600;
        int j = q & 7, l = (q >> 3) & 63, kc = (q >> 9) & 7, nt = q >> 12;
        int n = nt * 16 + (l & 15), k = kc * 32 + (l >> 4) * 8 + j;
        int cls = n >> 6, co = n & 63, p = k >> 6, ci = k & 63;
        int jh = -1, jw = -1;
        if (cls == 0)      { if (p == 0) { jh = 1; jw = 1; } }
        else if (cls == 1) { if (p == 1) { jh = 1; jw = 0; } else if (p == 0) { jh = 1; jw = 2; } }
        else if (cls == 2) { if (p == 2) { jh = 0; jw = 1; } else if (p == 0) { jh = 2; jw = 1; } }
        else { if (p == 3) { jh = 0; jw = 0; } else if (p == 2) { jh = 0; jw = 2; }
               else if (p == 1) { jh = 2; jw = 0; } else { jh = 2; jw = 2; } }
        float v = (jh >= 0) ? dw1[((co * 64 + ci) * 3 + jh) * 3 + jw] : 0.f;
        wB1[q] = f2bf(v);
    } else if (i < 251904) {
        // B2: tconv2 zero-padded (nt8, kc8, lane64, j8)
        int q = i - 219136;
        int j = q & 7, l = (q >> 3) & 63, kc = (q >> 9) & 7, nt = q >> 12;
        int n = nt * 16 + (l & 15), k = kc * 32 + (l >> 4) * 8 + j;
        int cls = n >> 5, co = n & 31, p = k >> 6, ci = k & 63;
        int jh = -1, jw = -1;
        if (cls == 0)      { if (p == 0) { jh = 1; jw = 1; } }
        else if (cls == 1) { if (p == 1) { jh = 1; jw = 0; } else if (p == 0) { jh = 1; jw = 2; } }
        else if (cls == 2) { if (p == 2) { jh = 0; jw = 1; } else if (p == 0) { jh = 2; jw = 1; } }
        else { if (p == 3) { jh = 0; jw = 0; } else if (p == 2) { jh = 0; jw = 2; }
               else if (p == 1) { jh = 2; jw = 0; } else { jh = 2; jw = 2; } }
        float v = (jh >= 0) ? dw2[((co * 64 + ci) * 3 + jh) * 3 + jw] : 0.f;
        wB2[q] = f2bf(v);
    } else if (i < 264192) {
        // B3: conv3 split (nt4, kc6, lane64, j8); K2=192 = [hi64|lo64|hi64]
        int q = i - 251904;
        int j = q & 7, lane = (q >> 3) & 63;
        int kc = (q >> 9) % 6, nt = (q >> 9) / 6;
        int k = kc * 32 + ((lane >> 4) << 3) + j;
        int n = nt * 16 + (lane & 15);
        int part = (k < 64) ? 0 : (k < 128) ? 1 : 0;
        int kk = (k < 64) ? k : (k < 128) ? k - 64 : k - 128;
        float v = ew3[n * 64 + kk];
        unsigned short hi = f2bf(v);
        wB3[q] = part ? f2bf(v - bf2f(hi)) : hi;
    } else if (i < 264704) {
        int k = i - 264192;
        const float* r = cb + k * 64;
        float s = 0.f;
#pragma unroll
        for (int c = 0; c < 64; ++c) s += r[c] * r[c];
        cn[k] = s;
    } else if (i == 264704) {
        *loss = 0.f;
    }
}

// ---- conv1: x (bc,50,50) -> h1 (bc,25,25,32) f32, relu ---------------------
__global__ __launch_bounds__(256) void k_conv1(const float* __restrict__ x,
                                               const float* __restrict__ w,
                                               const float* __restrict__ b,
                                               float* __restrict__ h1, int total) {
    __shared__ float4 wl4[72];
    float* wl = (float*)wl4;
    int tid = threadIdx.x;
    for (int t = tid; t < 288; t += 256) {
        int tap = t >> 5, co = t & 31;
        wl[t] = w[co * 9 + tap];
    }
    __syncthreads();
    int pix = blockIdx.x * 256 + tid;
    if (pix >= total) return;
    int n = pix / 625, p = pix % 625, oh = p / 25, ow = p % 25;
    const float* xp = x + (size_t)n * 2500;
    float4 a[8];
#pragma unroll
    for (int j = 0; j < 8; ++j) a[j] = ((const float4*)b)[j];
#pragma unroll
    for (int kh = 0; kh < 3; ++kh) {
        int ih = 2 * oh - 1 + kh;
        if ((unsigned)ih >= 50u) continue;
#pragma unroll
        for (int kw = 0; kw < 3; ++kw) {
            int iw = 2 * ow - 1 + kw;
            if ((unsigned)iw >= 50u) continue;
            float v = xp[ih * 50 + iw];
            int tap = kh * 3 + kw;
#pragma unroll
            for (int j = 0; j < 8; ++j) {
                float4 ww = wl4[tap * 8 + j];
                a[j].x += v * ww.x; a[j].y += v * ww.y;
                a[j].z += v * ww.z; a[j].w += v * ww.w;
            }
        }
    }
    float4* op = (float4*)(h1 + (size_t)pix * 32);
#pragma unroll
    for (int j = 0; j < 8; ++j) {
        float4 r;
        r.x = fmaxf(a[j].x, 0.f); r.y = fmaxf(a[j].y, 0.f);
        r.z = fmaxf(a[j].z, 0.f); r.w = fmaxf(a[j].w, 0.f);
        op[j] = r;
    }
}

// ---- enc_m: fused conv2(k3s2p1)+relu+conv3(1x1), split-bf16 MFMA (M=16) ----
__global__ __launch_bounds__(256) void k_enc_m(const float* __restrict__ h1,
                                               const unsigned short* __restrict__ B2n,
                                               const unsigned short* __restrict__ B3,
                                               const float* __restrict__ b2,
                                               const float* __restrict__ b3,
                                               float* __restrict__ z, int npix) {
    __shared__ short a1[16 * 872];
    __shared__ short a2[16 * 200];
    __shared__ float cz[16 * 68];
    int tid = threadIdx.x, blk = blockIdx.x;
    {
        int m = tid >> 4, chunk = tid & 15;
        if (chunk < 9) {
            int pix = blk * 16 + m;
            float4 v[8];
            const float4 zero = {0.f, 0.f, 0.f, 0.f};
            bool ok = false;
            if (pix < npix) {
                int n = pix / 169, p = pix % 169, oh = p / 13, ow = p % 13;
                int kh = chunk / 3, kw = chunk % 3;
                int ih = 2 * oh - 1 + kh, iw = 2 * ow - 1 + kw;
                ok = ((unsigned)ih < 25u) && ((unsigned)iw < 25u);
                if (ok) {
                    const float4* ip = (const float4*)(h1 + (((size_t)n * 25 + ih) * 25 + iw) * 32);
#pragma unroll
                    for (int c4 = 0; c4 < 8; ++c4) v[c4] = ip[c4];
                }
            }
            if (!ok) {
#pragma unroll
                for (int c4 = 0; c4 < 8; ++c4) v[c4] = zero;
            }
            unsigned short hi[32], lo[32];
#pragma unroll
            for (int c4 = 0; c4 < 8; ++c4) {
                float vv[4] = {v[c4].x, v[c4].y, v[c4].z, v[c4].w};
#pragma unroll
                for (int e = 0; e < 4; ++e) {
                    int ci = c4 * 4 + e;
                    unsigned short h = f2bf(vv[e]);
                    hi[ci] = h;
                    lo[ci] = f2bf(vv[e] - bf2f(h));
                }
            }
            short* row = a1 + m * 872 + chunk * 32;
            i4v* d0 = (i4v*)row;
            i4v* d1 = (i4v*)(row + 288);
            i4v* d2 = (i4v*)(row + 576);
#pragma unroll
            for (int g = 0; g < 4; ++g) {
                i4v ph, pl;
#pragma unroll
                for (int e = 0; e < 4; ++e) {
                    int b0 = g * 8 + e * 2;
                    ph[e] = (int)((unsigned)hi[b0] | ((unsigned)hi[b0 + 1] << 16));
                    pl[e] = (int)((unsigned)lo[b0] | ((unsigned)lo[b0 + 1] << 16));
                }
                d0[g] = ph; d1[g] = ph; d2[g] = pl;
            }
        }
    }
    __syncthreads();
    int wave = tid >> 6, lane = tid & 63;
    int arow1 = (lane & 15) * 872 + (lane >> 4) * 8;
    f4v acc = (f4v){0.f, 0.f, 0.f, 0.f};
#pragma unroll
    for (int kc = 0; kc < 27; ++kc) {
        s8v a = *(const s8v*)(a1 + arow1 + kc * 32);
        s8v b = *(const s8v*)((const short*)B2n + ((size_t)((wave * 27 + kc) * 64 + lane)) * 8);
        acc = __builtin_amdgcn_mfma_f32_16x16x32_bf16(a, b, acc, 0, 0, 0);
    }
    {
        float bv = b2[wave * 16 + (lane & 15)];
        int n = wave * 16 + (lane & 15);
#pragma unroll
        for (int r = 0; r < 4; ++r) {
            int m = (lane >> 4) * 4 + r;
            float h = fmaxf(acc[r] + bv, 0.f);
            unsigned short hh = f2bf(h);
            unsigned short ll = f2bf(h - bf2f(hh));
            a2[m * 200 + n] = (short)hh;
            a2[m * 200 + 64 + n] = (short)hh;
            a2[m * 200 + 128 + n] = (short)ll;
        }
    }
    __syncthreads();
    int arow2 = (lane & 15) * 200 + (lane >> 4) * 8;
    f4v acc2 = (f4v){0.f, 0.f, 0.f, 0.f};
#pragma unroll
    for (int kc = 0; kc < 6; ++kc) {
        s8v a = *(const s8v*)(a2 + arow2 + kc * 32);
        s8v b = *(const s8v*)((const short*)B3 + ((size_t)((wave * 6 + kc) * 64 + lane)) * 8);
        acc2 = __builtin_amdgcn_mfma_f32_16x16x32_bf16(a, b, acc2, 0, 0, 0);
    }
    {
        float bv = b3[wave * 16 + (lane & 15)];
        int n = wave * 16 + (lane & 15);
#pragma unroll
        for (int r = 0; r < 4; ++r) {
            int m = (lane >> 4) * 4 + r;
            cz[m * 68 + n] = acc2[r] + bv;
        }
    }
    __syncthreads();
    {
        int m = tid >> 4, c4 = tid & 15;
        int pix = blk * 16 + m;
        if (pix < npix) {
            float4 v = *(float4*)(cz + m * 68 + c4 * 4);
            *(float4*)(z + (size_t)pix * 64 + c4 * 4) = v;
        }
    }
}

// ---- vq_m: MFMA distance GEMM + fused argmin + q gather + loss (M=32) ------
__global__ __launch_bounds__(256) void k_vq_m(const float* __restrict__ z,
                                              const float* __restrict__ cb,
                                              const unsigned short* __restrict__ cbm,
                                              const float* __restrict__ cn,
                                              float* __restrict__ q,
                                              float* __restrict__ loss, int npix) {
    __shared__ short a_lds[32 * 200];
    __shared__ float reds[4 * 32];
    __shared__ int   redk[4 * 32];
    __shared__ int   bkf[32];
    __shared__ float lred[4];
    int tid = threadIdx.x, blk = blockIdx.x;
    {
        int m = tid >> 3, p = tid & 7;
        int pix = blk * 32 + m;
        unsigned short zh[8], zl[8];
        if (pix < npix) {
            const float* src = z + (size_t)pix * 64 + p * 8;
#pragma unroll
            for (int v = 0; v < 8; ++v) {
                float f = src[v];
                unsigned short h = f2bf(f);
                zh[v] = h; zl[v] = f2bf(f - bf2f(h));
            }
        } else {
#pragma unroll
            for (int v = 0; v < 8; ++v) { zh[v] = 0; zl[v] = 0; }
        }
        unsigned ph[4], pl[4];
#pragma unroll
        for (int v = 0; v < 4; ++v) {
            ph[v] = (unsigned)zh[2 * v] | ((unsigned)zh[2 * v + 1] << 16);
            pl[v] = (unsigned)zl[2 * v] | ((unsigned)zl[2 * v + 1] << 16);
        }
        short* row = a_lds + m * 200;
        i4v vh = (i4v){(int)ph[0], (int)ph[1], (int)ph[2], (int)ph[3]};
        i4v vl = (i4v){(int)pl[0], (int)pl[1], (int)pl[2], (int)pl[3]};
        *(i4v*)(row + p * 8) = vh;
        *(i4v*)(row + 64 + p * 8) = vh;
        *(i4v*)(row + 128 + p * 8) = vl;
    }
    __syncthreads();
    int wave = tid >> 6, lane = tid & 63;
    s8v af[2][6];
#pragma unroll
    for (int mt = 0; mt < 2; ++mt) {
        int arow = (mt * 16 + (lane & 15)) * 200 + (lane >> 4) * 8;
#pragma unroll
        for (int kc = 0; kc < 6; ++kc)
            af[mt][kc] = *(const s8v*)(a_lds + arow + kc * 32);
    }
    float bd[2][4];
    int bk[2][4];
#pragma unroll
    for (int mt = 0; mt < 2; ++mt)
#pragma unroll
        for (int r = 0; r < 4; ++r) { bd[mt][r] = 3.4e38f; bk[mt][r] = 0; }
#pragma unroll 2
    for (int nt = 0; nt < 8; ++nt) {
        int ntg = wave * 8 + nt;
        s8v bf[6];
#pragma unroll
        for (int kc = 0; kc < 6; ++kc)
            bf[kc] = *(const s8v*)((const short*)cbm + ((size_t)((ntg * 6 + kc) * 64 + lane)) * 8);
        f4v acc0 = (f4v){0.f, 0.f, 0.f, 0.f};
        f4v acc1 = (f4v){0.f, 0.f, 0.f, 0.f};
#pragma unroll
        for (int kc = 0; kc < 6; ++kc) {
            acc0 = __builtin_amdgcn_mfma_f32_16x16x32_bf16(af[0][kc], bf[kc], acc0, 0, 0, 0);
            acc1 = __builtin_amdgcn_mfma_f32_16x16x32_bf16(af[1][kc], bf[kc], acc1, 0, 0, 0);
        }
        int kcol = ntg * 16 + (lane & 15);
        float cnk = cn[kcol];
#pragma unroll
        for (int r = 0; r < 4; ++r) {
            float d0 = cnk - 2.f * acc0[r];
            if (d0 < bd[0][r]) { bd[0][r] = d0; bk[0][r] = kcol; }
            float d1 = cnk - 2.f * acc1[r];
            if (d1 < bd[1][r]) { bd[1][r] = d1; bk[1][r] = kcol; }
        }
    }
#pragma unroll
    for (int off = 1; off < 16; off <<= 1) {
#pragma unroll
        for (int mt = 0; mt < 2; ++mt)
#pragma unroll
            for (int r = 0; r < 4; ++r) {
                float od = __shfl_xor(bd[mt][r], off);
                int ok = __shfl_xor(bk[mt][r], off);
                if (od < bd[mt][r] || (od == bd[mt][r] && ok < bk[mt][r])) {
                    bd[mt][r] = od; bk[mt][r] = ok;
                }
            }
    }
    if ((lane & 15) == 0) {
#pragma unroll
        for (int mt = 0; mt < 2; ++mt)
#pragma unroll
            for (int r = 0; r < 4; ++r) {
                int m = mt * 16 + (lane >> 4) * 4 + r;
                reds[wave * 32 + m] = bd[mt][r];
                redk[wave * 32 + m] = bk[mt][r];
            }
    }
    __syncthreads();
    if (tid < 32) {
        float d0 = reds[tid]; int k0 = redk[tid];
#pragma unroll
        for (int w = 1; w < 4; ++w) {
            float dw = reds[w * 32 + tid]; int kw = redk[w * 32 + tid];
            if (dw < d0 || (dw == d0 && kw < k0)) { d0 = dw; k0 = kw; }
        }
        bkf[tid] = k0;
    }
    __syncthreads();
    float lsum = 0.f;
#pragma unroll
    for (int it = 0; it < 2; ++it) {
        int m = tid >> 3, c4 = (tid & 7) + it * 8;
        int pix = blk * 32 + m;
        if (pix < npix) {
            int k0 = bkf[m];
            float4 cq = ((const float4*)cb)[(size_t)k0 * 16 + c4];
            float4 zz = ((const float4*)(z + (size_t)pix * 64))[c4];
            float dx = cq.x - zz.x, dy = cq.y - zz.y, dz = cq.z - zz.z, dw = cq.w - zz.w;
            lsum += dx * dx + dy * dy + dz * dz + dw * dw;
            ((float4*)(q + (size_t)pix * 64))[c4] = cq;
        }
    }
#pragma unroll
    for (int off = 32; off > 0; off >>= 1) lsum += __shfl_down(lsum, off);
    if ((tid & 63) == 0) lred[tid >> 6] = lsum;
    __syncthreads();
    if (tid == 0) {
        float t = lred[0] + lred[1] + lred[2] + lred[3];
        atomicAdd(loss, t * (1.25f / 11075584.f));
    }
}

// ---- tconv1 MFMA: q f32 -> d1 bf16 (25,25,64), relu. M=32/block ------------
__global__ __launch_bounds__(256) void k_tconv1_m(const float* __restrict__ q,
                                                  const unsigned short* __restrict__ wB,
                                                  const float* __restrict__ bias,
                                                  unsigned short* __restrict__ d1,
                                                  int nquad) {
    __shared__ short a_lds[32 * 264];
    __shared__ short c_lds[32 * 264];
    int tid = threadIdx.x, blk = blockIdx.x;
#pragma unroll
    for (int pass = 0; pass < 4; ++pass) {
        int idx = tid + pass * 256;
        int m = idx >> 5, sub = idx & 31;
        int qg = blk * 32 + m;
        int p = sub >> 3, ci0 = (sub & 7) * 8;
        unsigned short t8[8];
        bool have = false;
        if (qg < nquad) {
            int img = qg / 169, r = qg % 169, qm = r / 13, qw = r % 13;
            int sm = qm + (p >> 1), sw = qw + (p & 1);
            if (sm < 13 && sw < 13) {
                const float* src = q + (((size_t)img * 13 + sm) * 13 + sw) * 64 + ci0;
#pragma unroll
                for (int v = 0; v < 8; ++v) t8[v] = f2bf(src[v]);
                have = true;
            }
        }
        if (!have) {
#pragma unroll
            for (int v = 0; v < 8; ++v) t8[v] = 0;
        }
        i4v pk;
#pragma unroll
        for (int e = 0; e < 4; ++e)
            pk[e] = (int)((unsigned)t8[2 * e] | ((unsigned)t8[2 * e + 1] << 16));
        *(i4v*)(a_lds + m * 264 + sub * 8) = pk;
    }
    __syncthreads();
    int wave = tid >> 6, lane = tid & 63;
    f4v acc[2][4];
#pragma unroll
    for (int mt = 0; mt < 2; ++mt)
#pragma unroll
        for (int i = 0; i < 4; ++i) acc[mt][i] = (f4v){0.f, 0.f, 0.f, 0.f};
    float bv[4];
#pragma unroll
    for (int i = 0; i < 4; ++i) bv[i] = bias[((wave * 4 + i) * 16 + (lane & 15)) & 63];
#pragma unroll
    for (int kc = 0; kc < 8; ++kc) {
        s8v a0 = *(const s8v*)(a_lds + ((lane & 15)) * 264 + (lane >> 4) * 8 + kc * 32);
        s8v a1 = *(const s8v*)(a_lds + (16 + (lane & 15)) * 264 + (lane >> 4) * 8 + kc * 32);
#pragma unroll
        for (int i = 0; i < 4; ++i) {
            int nt = wave * 4 + i;
            s8v b = *(const s8v*)((const short*)wB + ((size_t)((nt * 8 + kc) * 64 + lane)) * 8);
            acc[0][i] = __builtin_amdgcn_mfma_f32_16x16x32_bf16(a0, b, acc[0][i], 0, 0, 0);
            acc[1][i] = __builtin_amdgcn_mfma_f32_16x16x32_bf16(a1, b, acc[1][i], 0, 0, 0);
        }
    }
#pragma unroll
    for (int mt = 0; mt < 2; ++mt)
#pragma unroll
        for (int i = 0; i < 4; ++i) {
            int n = (wave * 4 + i) * 16 + (lane & 15);
#pragma unroll
            for (int r2 = 0; r2 < 4; ++r2) {
                int m = mt * 16 + (lane >> 4) * 4 + r2;
                float v = fmaxf(acc[mt][i][r2] + bv[i], 0.f);
                c_lds[m * 264 + n] = (short)f2bf(v);
            }
        }
    __syncthreads();
#pragma unroll
    for (int pass = 0; pass < 4; ++pass) {
        int ch = tid + pass * 256;
        int m = ch >> 5, cpart = ch & 31;
        int qg = blk * 32 + m;
        if (qg >= nquad) continue;
        int img = qg / 169, r = qg % 169, qm = r / 13, qw = r % 13;
        int cls = cpart >> 3, co8 = (cpart & 7) * 8;
        int oh = 2 * qm + (cls >> 1), ow = 2 * qw + (cls & 1);
        if (oh >= 25 || ow >= 25) continue;
        i4v val = *(i4v*)(c_lds + m * 264 + cls * 64 + co8);
        *(i4v*)(d1 + (((size_t)img * 25 + oh) * 25 + ow) * 64 + co8) = val;
    }
}

// ---- tconv2 MFMA: d1 bf16 -> d2 bf16 (50,50,32), relu. M=32/block ----------
__global__ __launch_bounds__(256) void k_tconv2_m(const unsigned short* __restrict__ d1,
                                                  const unsigned short* __restrict__ wB,
                                                  const float* __restrict__ bias,
                                                  unsigned short* __restrict__ d2,
                                                  int nquad) {
    __shared__ short a_lds[32 * 264];
    __shared__ short c_lds[32 * 136];
    int tid = threadIdx.x, blk = blockIdx.x;
#pragma unroll
    for (int pass = 0; pass < 4; ++pass) {
        int idx = tid + pass * 256;
        int m = idx >> 5, sub = idx & 31;
        int qg = blk * 32 + m;
        int p = sub >> 3, ci0 = (sub & 7) * 8;
        i4v v = (i4v){0, 0, 0, 0};
        if (qg < nquad) {
            int img = qg / 625, r = qg % 625, qm = r / 25, qw = r % 25;
            int sm = qm + (p >> 1), sw = qw + (p & 1);
            if (sm < 25 && sw < 25)
                v = *(const i4v*)(d1 + (((size_t)img * 25 + sm) * 25 + sw) * 64 + ci0);
        }
        *(i4v*)(a_lds + m * 264 + sub * 8) = v;
    }
    __syncthreads();
    int wave = tid >> 6, lane = tid & 63;
    f4v acc[2][2];
#pragma unroll
    for (int mt = 0; mt < 2; ++mt)
#pragma unroll
        for (int i = 0; i < 2; ++i) acc[mt][i] = (f4v){0.f, 0.f, 0.f, 0.f};
    float bv[2];
#pragma unroll
    for (int i = 0; i < 2; ++i) bv[i] = bias[((wave * 2 + i) * 16 + (lane & 15)) & 31];
#pragma unroll
    for (int kc = 0; kc < 8; ++kc) {
        s8v a0 = *(const s8v*)(a_lds + ((lane & 15)) * 264 + (lane >> 4) * 8 + kc * 32);
        s8v a1 = *(const s8v*)(a_lds + (16 + (lane & 15)) * 264 + (lane >> 4) * 8 + kc * 32);
#pragma unroll
        for (int i = 0; i < 2; ++i) {
            int nt = wave * 2 + i;
            s8v b = *(const s8v*)((const short*)wB + ((size_t)((nt * 8 + kc) * 64 + lane)) * 8);
            acc[0][i] = __builtin_amdgcn_mfma_f32_16x16x32_bf16(a0, b, acc[0][i], 0, 0, 0);
            acc[1][i] = __builtin_amdgcn_mfma_f32_16x16x32_bf16(a1, b, acc[1][i], 0, 0, 0);
        }
    }
#pragma unroll
    for (int mt = 0; mt < 2; ++mt)
#pragma unroll
        for (int i = 0; i < 2; ++i) {
            int n = (wave * 2 + i) * 16 + (lane & 15);
#pragma unroll
            for (int r2 = 0; r2 < 4; ++r2) {
                int m = mt * 16 + (lane >> 4) * 4 + r2;
                float v = fmaxf(acc[mt][i][r2] + bv[i], 0.f);
                c_lds[m * 136 + n] = (short)f2bf(v);
            }
        }
    __syncthreads();
#pragma unroll
    for (int pass = 0; pass < 2; ++pass) {
        int ch = tid + pass * 256;
        int m = ch >> 4, cpart = ch & 15;
        int qg = blk * 32 + m;
        if (qg >= nquad) continue;
        int img = qg / 625, r = qg % 625, qm = r / 25, qw = r % 25;
        int cls = cpart >> 2, co8 = (cpart & 3) * 8;
        int oh = 2 * qm + (cls >> 1), ow = 2 * qw + (cls & 1);
        i4v val = *(i4v*)(c_lds + m * 136 + cls * 32 + co8);
        *(i4v*)(d2 + (((size_t)img * 50 + oh) * 50 + ow) * 32 + co8) = val;
    }
}

// ---- convf: d2 bf16 (bc,50,50,32) -> out f32 (bc,50,50), sigmoid -----------
__global__ __launch_bounds__(256) void k_convf(const unsigned short* __restrict__ in,
                                               const float* __restrict__ w,  // dw3 (1,32,3,3)
                                               const float* __restrict__ b,
                                               float* __restrict__ out, int total) {
    __shared__ float wl[288];  // [tap9][ci32]
    int tid = threadIdx.x;
    for (int t = tid; t < 288; t += 256) {
        int tap = t >> 5, ci = t & 31;
        wl[t] = w[ci * 9 + tap];
    }
    __syncthreads();
    int pix = blockIdx.x * 256 + tid;
    if (pix >= total) return;
    int n = pix / 2500, p = pix % 2500, oh = p / 50, ow = p % 50;
    float acc = b[0];
#pragma unroll
    for (int kh = 0; kh < 3; ++kh) {
        int ih = oh - 1 + kh;
        if ((unsigned)ih >= 50u) continue;
#pragma unroll
        for (int kw = 0; kw < 3; ++kw) {
            int iw = ow - 1 + kw;
            if ((unsigned)iw >= 50u) continue;
            const float* wt = wl + (kh * 3 + kw) * 32;
            const i4v* ip4 = (const i4v*)(in + (((size_t)n * 50 + ih) * 50 + iw) * 32);
#pragma unroll
            for (int c8 = 0; c8 < 4; ++c8) {
                i4v u = ip4[c8];
#pragma unroll
                for (int e = 0; e < 4; ++e) {
                    unsigned uu = (unsigned)u[e];
                    float x0 = __builtin_bit_cast(float, uu << 16);
                    float x1 = __builtin_bit_cast(float, uu & 0xffff0000u);
                    acc = fmaf(x0, wt[c8 * 8 + e * 2], acc);
                    acc = fmaf(x1, wt[c8 * 8 + e * 2 + 1], acc);
                }
            }
        }
    }
    out[pix] = 1.f / (1.f + expf(-acc));
}

extern "C" void kernel_launch(void* const* d_in, const int* in_sizes, int n_in,
                              void* d_out, int out_size, void* d_ws, size_t ws_size,
                              hipStream_t stream) {
    const float* x   = (const float*)d_in[0];
    const float* ew1 = (const float*)d_in[1];
    const float* eb1 = (const float*)d_in[2];
    const float* ew2 = (const float*)d_in[3];
    const float* eb2 = (const float*)d_in[4];
    const float* ew3 = (const float*)d_in[5];
    const float* eb3 = (const float*)d_in[6];
    const float* cb  = (const float*)d_in[7];
    const float* dw1 = (const float*)d_in[8];
    const float* db1 = (const float*)d_in[9];
    const float* dw2 = (const float*)d_in[10];
    const float* db2 = (const float*)d_in[11];
    const float* dw3 = (const float*)d_in[12];
    const float* db3 = (const float*)d_in[13];
    float* out = (float*)d_out;
    float* loss = out + 2560000;

    float* ws = (float*)d_ws;
    float* cn = ws;                                        // 512 f
    unsigned short* wB1  = (unsigned short*)(ws + 512);    // 65536 sh
    unsigned short* wB2  = (unsigned short*)(ws + 33280);  // 32768 sh
    unsigned short* wB2n = (unsigned short*)(ws + 49664);  // 55296 sh
    unsigned short* wB3  = (unsigned short*)(ws + 77312);  // 12288 sh
    unsigned short* cbm  = (unsigned short*)(ws + 83456);  // 98304 sh
    const size_t tw_floats = 132608;

    const int B = 1024;
    // regA 40000 f/img: h1 (20000), q (10816), d2-bf16 (80000 sh)
    // regB 20000 f/img: z (10816), d1-bf16 (40000 sh)
    const size_t A_per = 40000, B_per = 20000;
    size_t avail = (ws_size / 4 > tw_floats) ? ws_size / 4 - tw_floats : 0;
    int BC = (int)(avail / (A_per + B_per));
    if (BC > B) BC = B;
    if (BC < 1) BC = 1;
    float* regA = ws + tw_floats;
    float* regB = regA + (size_t)BC * A_per;

    k_prep_all<<<1035, 256, 0, stream>>>(cb, ew2, ew3, dw1, dw2,
                                         cbm, wB2n, wB1, wB2, wB3, cn, loss);

    for (int n0 = 0; n0 < B; n0 += BC) {
        int bc = (B - n0 < BC) ? (B - n0) : BC;
        const float* xch = x + (size_t)n0 * 2500;

        int t1 = bc * 625;   // conv1: x -> h1 (regA)
        k_conv1<<<(t1 + 255) / 256, 256, 0, stream>>>(xch, ew1, eb1, regA, t1);

        int npix = bc * 169;
        // fused conv2+conv3 MFMA (M=16): h1 (regA) -> z (regB)
        k_enc_m<<<(npix + 15) / 16, 256, 0, stream>>>(regA, wB2n, wB3, eb2, eb3, regB, npix);

        // MFMA VQ (M=32): z (regB) -> q (regA) + loss
        k_vq_m<<<(npix + 31) / 32, 256, 0, stream>>>(regB, cb, cbm, cn, regA, loss, npix);

        // tconv1 MFMA: q (regA f32) -> d1 (regB bf16)
        unsigned short* d1 = (unsigned short*)regB;
        k_tconv1_m<<<(npix + 31) / 32, 256, 0, stream>>>(regA, wB1, db1, d1, npix);

        // tconv2 MFMA: d1 (regB bf16) -> d2 (regA bf16)
        int nq2 = bc * 625;
        unsigned short* d2 = (unsigned short*)regA;
        k_tconv2_m<<<(nq2 + 31) / 32, 256, 0, stream>>>(d1, wB2, db2, d2, nq2);

        int t6 = bc * 2500;  // convf: d2 bf16 (regA) -> out
        k_convf<<<(t6 + 255) / 256, 256, 0, stream>>>(d2, dw3, db3, out + (size_t)n0 * 2500, t6);
    }
}